// Round 7
// baseline (222.132 us; speedup 1.0000x reference)
//
#include <hip/hip_runtime.h>
#include <stdint.h>

// ---- types ----
typedef _Float16 f16x8 __attribute__((ext_vector_type(8)));
typedef _Float16 f16x4 __attribute__((ext_vector_type(4)));
typedef __fp16 h16x2 __attribute__((ext_vector_type(2)));  // cvt_pkrtz return type
typedef float f32x4 __attribute__((ext_vector_type(4)));
typedef float f32x16 __attribute__((ext_vector_type(16)));

#define SEQ 2048
#define NHEADS 8

// async global->LDS, 16B per lane, LDS dest = wave-uniform base + lane*16
#define GLOAD_LDS16(gp, lp)                                                        \
  __builtin_amdgcn_global_load_lds(                                                \
      (const __attribute__((address_space(1))) void*)(uintptr_t)(const void*)(gp), \
      (__attribute__((address_space(3))) void*)(uintptr_t)(void*)(lp), 16, 0, 0)

// pinned global->reg 16B load (per-lane address), literal offset.
// "=&v" EARLY-CLOBBER is load-bearing: without it, a dying address operand (e.g. the
// last Q load) may be allocated overlapping the dest pair -> dst-over-vaddr VMEM load
// -> unsafe under XNACK replay -> device fault (suspected r5/r6 container deaths).
#define GLD16(dst, ptr, imm) \
  asm volatile("global_load_dwordx4 %0, %1, off offset:%c2" : "=&v"(dst) : "v"(ptr), "i"(imm))

// counted vmem wait + scheduler fence: nothing (esp. MFMA reading asm-loaded regs)
// may hoist above this point (rule #18)
#define VMW(n)                                                     \
  do {                                                             \
    asm volatile("s_waitcnt vmcnt(%c0)" ::"i"(n) : "memory");      \
    __builtin_amdgcn_sched_barrier(0);                             \
  } while (0)

__device__ __forceinline__ f16x4 pack4(float a, float b, float c, float d) {
  h16x2 lo = __builtin_amdgcn_cvt_pkrtz(a, b);
  h16x2 hi = __builtin_amdgcn_cvt_pkrtz(c, d);
  f16x4 o;
  o.x = (_Float16)lo.x; o.y = (_Float16)lo.y;
  o.z = (_Float16)hi.x; o.w = (_Float16)hi.y;
  return o;
}

// ---------------- fp32 -> f16 convert (x + 4 weights, one launch) ----------------
__global__ void cvt_all_kernel(const float* __restrict__ x, const float* __restrict__ wq,
                               const float* __restrict__ wk, const float* __restrict__ wv,
                               const float* __restrict__ wo, _Float16* __restrict__ xh,
                               _Float16* __restrict__ wh) {
  int i = blockIdx.x * 256 + threadIdx.x;  // 0 .. 1310719 (f4 units)
  const float* src;
  _Float16* dst;
  int off;
  if (i < 1048576) {
    src = x; dst = xh; off = i;
  } else {
    int j = i - 1048576;
    int sel = j >> 16;
    off = j & 65535;
    src = (sel == 0) ? wq : (sel == 1) ? wk : (sel == 2) ? wv : wo;
    dst = wh + (size_t)sel * 262144;
  }
  float4 v = ((const float4*)src)[off];
  ((f16x4*)dst)[off] = pack4(v.x, v.y, v.z, v.w);
}

// ---------------- shared 128x128 B^T GEMM tile core (f16, double-buffered DMA) ----------------
__device__ __forceinline__ void gemm_tile_bt(const _Float16* __restrict__ A,
                                             const _Float16* __restrict__ B,
                                             int m0, int n0,
                                             _Float16* lds,
                                             f32x4 (&acc)[4][4]) {
  const int tid = threadIdx.x;
  const int w = tid >> 6, lane = tid & 63;
  const int wr = w >> 1, wc = w & 1;
  const int lrow = lane & 15, q = lane >> 4;
  const int snb = w * 32 + (lane >> 3);
  const int scb = lane & 7;

#pragma unroll
  for (int i = 0; i < 4; ++i)
#pragma unroll
    for (int j = 0; j < 4; ++j)
#pragma unroll
      for (int r = 0; r < 4; ++r) acc[i][j][r] = 0.f;

#pragma unroll
  for (int t = 0; t < 4; ++t) {
    int n = snb + t * 8;
    int cbg = scb ^ (n & 7);
    GLOAD_LDS16(A + (size_t)(m0 + n) * 512 + cbg * 8, lds + (w * 32 + t * 8) * 64);
    GLOAD_LDS16(B + (size_t)(n0 + n) * 512 + cbg * 8, lds + 8192 + (w * 32 + t * 8) * 64);
  }

  for (int kt = 0; kt < 8; ++kt) {  // K=512, BK=64
    __syncthreads();
    if (kt < 7) {
      _Float16* nb = lds + ((kt + 1) & 1) * 16384;
#pragma unroll
      for (int t = 0; t < 4; ++t) {
        int n = snb + t * 8;
        int cbg = scb ^ (n & 7);
        GLOAD_LDS16(A + (size_t)(m0 + n) * 512 + (kt + 1) * 64 + cbg * 8, nb + (w * 32 + t * 8) * 64);
        GLOAD_LDS16(B + (size_t)(n0 + n) * 512 + (kt + 1) * 64 + cbg * 8, nb + 8192 + (w * 32 + t * 8) * 64);
      }
    }
    _Float16* As = lds + (kt & 1) * 16384;
    _Float16* Bs = As + 8192;

    f16x8 af[4][2], bfr[4][2];
#pragma unroll
    for (int i = 0; i < 4; ++i) {
      int m = wr * 64 + i * 16 + lrow;
#pragma unroll
      for (int kk = 0; kk < 2; ++kk) {
        int cb = (kk * 4 + q) ^ (m & 7);
        af[i][kk] = *(const f16x8*)(As + m * 64 + cb * 8);
      }
    }
#pragma unroll
    for (int j = 0; j < 4; ++j) {
      int n = wc * 64 + j * 16 + lrow;
#pragma unroll
      for (int kk = 0; kk < 2; ++kk) {
        int cb = (kk * 4 + q) ^ (n & 7);
        bfr[j][kk] = *(const f16x8*)(Bs + n * 64 + cb * 8);
      }
    }
#pragma unroll
    for (int i = 0; i < 4; ++i)
#pragma unroll
      for (int j = 0; j < 4; ++j) {
        acc[i][j] = __builtin_amdgcn_mfma_f32_16x16x32_f16(af[i][0], bfr[j][0], acc[i][j], 0, 0, 0);
        acc[i][j] = __builtin_amdgcn_mfma_f32_16x16x32_f16(af[i][1], bfr[j][1], acc[i][j], 0, 0, 0);
      }
  }
}

// ---------------- QKV projection ----------------
__global__ __launch_bounds__(256, 2) void qkv_kernel(
    const _Float16* __restrict__ xb, const _Float16* __restrict__ Wq,
    const _Float16* __restrict__ Wk, const _Float16* __restrict__ Wv,
    _Float16* __restrict__ Qo, _Float16* __restrict__ Ko, _Float16* __restrict__ Vto) {
  __shared__ _Float16 pool[32768];  // 64 KB dbuf staging; bounce [128][136] aliases
  const int z = blockIdx.z;
  f32x4 acc[4][4];
  const int tid = threadIdx.x, w = tid >> 6, lane = tid & 63;
  const int wr = w >> 1, wc = w & 1, lcol = lane & 15, q = lane >> 4;

  if (z < 2) {
    const int m0 = blockIdx.y * 128;  // out-feature tile
    const int n0 = blockIdx.x * 128;  // s tile
    gemm_tile_bt((z == 0) ? Wq : Wk, xb, m0, n0, pool, acc);
    _Float16* outp = (z == 0) ? Qo : Ko;
    __syncthreads();
#pragma unroll
    for (int i = 0; i < 4; ++i) {
      int cl = wr * 64 + i * 16 + q * 4;
#pragma unroll
      for (int j = 0; j < 4; ++j) {
        int s = wc * 64 + j * 16 + lcol;
        *(f16x4*)(pool + s * 136 + cl) =
            pack4(acc[i][j][0], acc[i][j][1], acc[i][j][2], acc[i][j][3]);
      }
    }
    __syncthreads();
#pragma unroll
    for (int it = 0; it < 16; ++it) {
      int srow = it * 8 + (tid >> 5);
      int ch = tid & 31;
      f16x4 v = *(const f16x4*)(pool + srow * 136 + ch * 4);
      *(f16x4*)(outp + (size_t)(n0 + srow) * 512 + m0 + ch * 4) = v;
    }
  } else {
    const int m0 = blockIdx.x * 128;  // s tile
    const int n0 = blockIdx.y * 128;  // feature tile
    gemm_tile_bt(xb, Wv, m0, n0, pool, acc);
    const int bb = m0 >> 11, sl0 = m0 & 2047;
    __syncthreads();
#pragma unroll
    for (int i = 0; i < 4; ++i) {
      int s0 = wr * 64 + i * 16 + q * 4;
#pragma unroll
      for (int j = 0; j < 4; ++j) {
        int c = wc * 64 + j * 16 + lcol;
        *(f16x4*)(pool + c * 136 + s0) =
            pack4(acc[i][j][0], acc[i][j][1], acc[i][j][2], acc[i][j][3]);
      }
    }
    __syncthreads();
#pragma unroll
    for (int it = 0; it < 16; ++it) {
      int crow = it * 8 + (tid >> 5);
      int ch = tid & 31;
      int cg = n0 + crow, h = cg >> 6, d = cg & 63;
      f16x4 v = *(const f16x4*)(pool + crow * 136 + ch * 4);
      *(f16x4*)(Vto + ((size_t)((bb * NHEADS + h) * 64 + d)) * SEQ + sl0 + ch * 4) = v;
    }
  }
}

// ---------------- attention window compute (regs in -> oacc) ----------------
// vb order: [0]=ww0,t0  [1]=ww0,t1  [2]=ww1,t0  [3]=ww1,t1
__device__ __forceinline__ void attn_window(const f16x8 (&ka)[4], const f16x8 (&vb)[4],
                                            const f16x8 (&qb)[4], const f32x16& z16,
                                            f32x16& o0, f32x16& o1) {
  const float c1 = 0.18033688011112042f;  // (1/8)*log2(e); exp2 bias -1 = -11+10 (P x1024)
  __builtin_amdgcn_s_setprio(1);
  f32x16 s = __builtin_amdgcn_mfma_f32_32x32x16_f16(ka[0], qb[0], z16, 0, 0, 0);
  s = __builtin_amdgcn_mfma_f32_32x32x16_f16(ka[1], qb[1], s, 0, 0, 0);
  s = __builtin_amdgcn_mfma_f32_32x32x16_f16(ka[2], qb[2], s, 0, 0, 0);
  s = __builtin_amdgcn_mfma_f32_32x32x16_f16(ka[3], qb[3], s, 0, 0, 0);
  __builtin_amdgcn_s_setprio(0);

  float p[16];
#pragma unroll
  for (int r = 0; r < 16; ++r) {
    float wp = __builtin_amdgcn_exp2f(__builtin_fmaf(s[r], c1, -1.0f));
    float e = wp * 0.0009765625f;
    p[r] = __builtin_fmaf(wp, __builtin_fmaf(e, e, -e), wp);  // wp*(1-e+e^2)
  }

  f16x8 pa0, pa1;
  {
    h16x2 a0 = __builtin_amdgcn_cvt_pkrtz(p[0], p[1]);
    h16x2 a1 = __builtin_amdgcn_cvt_pkrtz(p[2], p[3]);
    h16x2 a2 = __builtin_amdgcn_cvt_pkrtz(p[4], p[5]);
    h16x2 a3 = __builtin_amdgcn_cvt_pkrtz(p[6], p[7]);
    pa0[0] = (_Float16)a0.x; pa0[1] = (_Float16)a0.y;
    pa0[2] = (_Float16)a1.x; pa0[3] = (_Float16)a1.y;
    pa0[4] = (_Float16)a2.x; pa0[5] = (_Float16)a2.y;
    pa0[6] = (_Float16)a3.x; pa0[7] = (_Float16)a3.y;
    h16x2 b0 = __builtin_amdgcn_cvt_pkrtz(p[8], p[9]);
    h16x2 b1 = __builtin_amdgcn_cvt_pkrtz(p[10], p[11]);
    h16x2 b2 = __builtin_amdgcn_cvt_pkrtz(p[12], p[13]);
    h16x2 b3 = __builtin_amdgcn_cvt_pkrtz(p[14], p[15]);
    pa1[0] = (_Float16)b0.x; pa1[1] = (_Float16)b0.y;
    pa1[2] = (_Float16)b1.x; pa1[3] = (_Float16)b1.y;
    pa1[4] = (_Float16)b2.x; pa1[5] = (_Float16)b2.y;
    pa1[6] = (_Float16)b3.x; pa1[7] = (_Float16)b3.y;
  }

  __builtin_amdgcn_s_setprio(1);
  o0 = __builtin_amdgcn_mfma_f32_32x32x16_f16(pa0, vb[0], o0, 0, 0, 0);
  o1 = __builtin_amdgcn_mfma_f32_32x32x16_f16(pa0, vb[1], o1, 0, 0, 0);
  o0 = __builtin_amdgcn_mfma_f32_32x32x16_f16(pa1, vb[2], o0, 0, 0, 0);
  o1 = __builtin_amdgcn_mfma_f32_32x32x16_f16(pa1, vb[3], o1, 0, 0, 0);
  __builtin_amdgcn_s_setprio(0);
}

// issue one window's 8 fragment loads (pinned asm) from set S's pointers, then bump
// the pointers by 2 windows (depth-2 rotation).
#define ISSUE_WIN(KA, VB, KP, VP0, VP1) \
  do {                                  \
    GLD16(KA[0], KP, 0);                \
    GLD16(KA[1], KP, 32);               \
    GLD16(KA[2], KP, 64);               \
    GLD16(KA[3], KP, 96);               \
    GLD16(VB[0], VP0, 0);               \
    GLD16(VB[1], VP1, 0);               \
    GLD16(VB[2], VP0, 32);              \
    GLD16(VB[3], VP1, 32);              \
    KP += 65536;                        \
    VP0 += 128;                         \
    VP1 += 128;                         \
  } while (0)

// ---------------- sigmoid attention: barrier-free streaming (K/V from L2 to regs) ----------------
// Grid 512 = (8 xcd) x (4 bh) x (16 qt). Each wave owns 32 q-rows and streams the full
// 2048-k range in 64 windows of 32 k. NO LDS staging, NO __syncthreads in the k-loop:
// K/V/Q fragments are loaded straight from global (L2-resident; same per-lane patterns
// the r4 LDS reads used, harness-verified) via pinned global_load_dwordx4, with a
// 2-deep window prefetch governed by counted s_waitcnt vmcnt(8) + sched_barrier(0).
// This removes the r1-r4 invariant: the per-kt all-wave DMA/barrier rendezvous.
__global__ __launch_bounds__(256, 2) void attn_kernel(
    const _Float16* __restrict__ Qw, const _Float16* __restrict__ Kw,
    const _Float16* __restrict__ Vtw, _Float16* __restrict__ Ow) {
  __shared__ _Float16 lds[9216];  // epilogue bounce only: [128][72]

  const int tid = threadIdx.x, wv = tid >> 6, lane = tid & 63;
  const int q31 = lane & 31, hi = lane >> 5;

  // XCD swizzle: 4 bh x 16 q-tiles per XCD (K/V stay L2-resident)
  const int L = blockIdx.x;
  const int xcd = L & 7, slot = L >> 3;
  const int bh = xcd * 4 + (slot >> 4), qt = slot & 15;
  const int b = bh >> 3, h = bh & 7;
  const int q0 = qt * 128;

  // K A-frag lane->row permutation: swap bits 2,3 of (lane&31). With this, the S^T
  // C-regs feed PV A-frags in order (verified r1-r4).
  const int klp = (q31 & 3) | ((q31 & 4) << 1) | ((q31 & 8) >> 1) | (q31 & 16);

  // per-lane global base addresses
  const char* qp = (const char*)Qw +
                   (size_t)(b * SEQ + q0 + wv * 32 + q31) * 1024 + h * 128 + hi * 16;
  const char* kpA = (const char*)Kw + (size_t)(b * SEQ + klp) * 1024 + h * 128 + hi * 16;
  const char* kpB = kpA + 32768;  // W1 = +32 k-rows
  const char* vp0A = (const char*)Vtw + (size_t)bh * 262144 + (size_t)q31 * 4096 + hi * 16;
  const char* vp1A = vp0A + 32 * 4096;  // t=1: d rows 32..63
  const char* vp0B = vp0A + 64;         // W1 = +32 k cols (2B each)
  const char* vp1B = vp1A + 64;

  f16x8 qb[4];
  GLD16(qb[0], qp, 0);
  GLD16(qb[1], qp, 32);
  GLD16(qb[2], qp, 64);
  GLD16(qb[3], qp, 96);

  f16x8 kaA[4], vbA[4], kaB[4], vbB[4];
  ISSUE_WIN(kaA, vbA, kpA, vp0A, vp1A);  // W0
  ISSUE_WIN(kaB, vbB, kpB, vp0B, vp1B);  // W1

  f32x16 oacc0, oacc1, z16;
#pragma unroll
  for (int r = 0; r < 16; ++r) { z16[r] = 0.f; oacc0[r] = 0.f; oacc1[r] = 0.f; }

  // steady state: compute set X (its 8 loads landed when <=8 remain outstanding),
  // then reissue X two windows ahead.
  for (int i = 0; i < 31; ++i) {
    VMW(8);  // A landed (only B's 8 may remain)
    attn_window(kaA, vbA, qb, z16, oacc0, oacc1);  // W(2i)
    ISSUE_WIN(kaA, vbA, kpA, vp0A, vp1A);          // W(2i+2)
    VMW(8);  // B landed
    attn_window(kaB, vbB, qb, z16, oacc0, oacc1);  // W(2i+1)
    ISSUE_WIN(kaB, vbB, kpB, vp0B, vp1B);          // W(2i+3)
  }
  VMW(8);
  attn_window(kaA, vbA, qb, z16, oacc0, oacc1);  // W62
  VMW(0);
  attn_window(kaB, vbB, qb, z16, oacc0, oacc1);  // W63

  // epilogue: descale, bounce through LDS (disjoint rows per wave), coalesced stores
  _Float16* Ob = lds;  // [128][72]
#pragma unroll
  for (int t = 0; t < 2; ++t) {
#pragma unroll
    for (int r = 0; r < 16; ++r) {
      int row = wv * 32 + (r & 3) + ((r >> 2) << 3) + hi * 4;
      int d = t * 32 + q31;
      float v = (t == 0) ? oacc0[r] : oacc1[r];
      Ob[row * 72 + d] = (_Float16)(v * 0.0009765625f);
    }
  }
  __syncthreads();
#pragma unroll
  for (int it = 0; it < 8; ++it) {
    int row = it * 16 + (tid >> 4);
    int ch = tid & 15;
    f16x4 v = *(const f16x4*)(Ob + row * 72 + ch * 4);
    *(f16x4*)(Ow + (size_t)(b * SEQ + q0 + row) * 512 + h * 64 + ch * 4) = v;
  }
}

// ---------------- output projection (fp32 out, coalesced) ----------------
__global__ __launch_bounds__(256, 2) void oproj_kernel(
    const _Float16* __restrict__ A, const _Float16* __restrict__ Wo,
    float* __restrict__ out) {
  __shared__ _Float16 pool[32768];  // 64 KB dbuf
  const int m0 = blockIdx.x * 128, n0 = blockIdx.y * 128;
  f32x4 acc[4][4];
  gemm_tile_bt(A, Wo, m0, n0, pool, acc);

  const int tid = threadIdx.x, w = tid >> 6, lane = tid & 63;
  const int wr = w >> 1, wc = w & 1, lcol = lane & 15, q = lane >> 4;
#pragma unroll
  for (int i = 0; i < 4; ++i) {
    int gm0 = m0 + wr * 64 + i * 16 + q * 4;
#pragma unroll
    for (int j = 0; j < 4; ++j) {
      int gn = n0 + wc * 64 + j * 16 + lcol;
#pragma unroll
      for (int r = 0; r < 4; ++r)
        out[(size_t)(gm0 + r) * 512 + gn] = acc[i][j][r];
    }
  }
}

// ---------------- launch ----------------
extern "C" void kernel_launch(void* const* d_in, const int* in_sizes, int n_in,
                              void* d_out, int out_size, void* d_ws, size_t ws_size,
                              hipStream_t stream) {
  const float* x = (const float*)d_in[0];
  const float* Wq = (const float*)d_in[1];
  const float* Wk = (const float*)d_in[2];
  const float* Wv = (const float*)d_in[3];
  const float* Wo = (const float*)d_in[4];
  float* out = (float*)d_out;
  char* ws = (char*)d_ws;

  _Float16* xh = (_Float16*)(ws + 0);          // 8 MB [8192][512]
  _Float16* wh = (_Float16*)(ws + 8388608);    // 4 x 512 KB (q,k,v,o)
  _Float16* Qw = (_Float16*)(ws + 10485760);   // 8 MB [8192][512]
  _Float16* Kw = (_Float16*)(ws + 18874368);   // 8 MB [8192][512]
  _Float16* Vtw = (_Float16*)(ws + 27262976);  // 8 MB [B,H,D,S]
  _Float16* Ow = (_Float16*)(ws + 35651584);   // 8 MB [8192][512]

  _Float16* wqh = wh;
  _Float16* wkh = wh + 262144;
  _Float16* wvh = wh + 524288;
  _Float16* woh = wh + 786432;

  cvt_all_kernel<<<5120, 256, 0, stream>>>(x, Wq, Wk, Wv, Wo, xh, wh);
  qkv_kernel<<<dim3(64, 4, 3), 256, 0, stream>>>(xh, wqh, wkh, wvh, Qw, Kw, Vtw);
  attn_kernel<<<512, 256, 0, stream>>>(Qw, Kw, Vtw, Ow);
  oproj_kernel<<<dim3(64, 4), 256, 0, stream>>>(Ow, woh, out);
}

// Round 8
// 155.925 us; speedup vs baseline: 1.4246x; 1.4246x over previous
//
#include <hip/hip_runtime.h>
#include <stdint.h>

// ---- types ----
typedef _Float16 f16x8 __attribute__((ext_vector_type(8)));
typedef _Float16 f16x4 __attribute__((ext_vector_type(4)));
typedef __fp16 h16x2 __attribute__((ext_vector_type(2)));  // cvt_pkrtz return type
typedef float f32x4 __attribute__((ext_vector_type(4)));
typedef float f32x16 __attribute__((ext_vector_type(16)));

#define SEQ 2048
#define NHEADS 8

// async global->LDS, 16B per lane, LDS dest = wave-uniform base + lane*16
#define GLOAD_LDS16(gp, lp)                                                        \
  __builtin_amdgcn_global_load_lds(                                                \
      (const __attribute__((address_space(1))) void*)(uintptr_t)(const void*)(gp), \
      (__attribute__((address_space(3))) void*)(uintptr_t)(void*)(lp), 16, 0, 0)

// counted vmem wait + scheduler fence: nothing below may hoist above this point
#define VMW(n)                                                     \
  do {                                                             \
    asm volatile("s_waitcnt vmcnt(%c0)" ::"i"(n) : "memory");      \
    __builtin_amdgcn_sched_barrier(0);                             \
  } while (0)

__device__ __forceinline__ f16x4 pack4(float a, float b, float c, float d) {
  h16x2 lo = __builtin_amdgcn_cvt_pkrtz(a, b);
  h16x2 hi = __builtin_amdgcn_cvt_pkrtz(c, d);
  f16x4 o;
  o.x = (_Float16)lo.x; o.y = (_Float16)lo.y;
  o.z = (_Float16)hi.x; o.w = (_Float16)hi.y;
  return o;
}

// ---------------- fp32 -> f16 convert (x + 4 weights, one launch) ----------------
__global__ void cvt_all_kernel(const float* __restrict__ x, const float* __restrict__ wq,
                               const float* __restrict__ wk, const float* __restrict__ wv,
                               const float* __restrict__ wo, _Float16* __restrict__ xh,
                               _Float16* __restrict__ wh) {
  int i = blockIdx.x * 256 + threadIdx.x;  // 0 .. 1310719 (f4 units)
  const float* src;
  _Float16* dst;
  int off;
  if (i < 1048576) {
    src = x; dst = xh; off = i;
  } else {
    int j = i - 1048576;
    int sel = j >> 16;
    off = j & 65535;
    src = (sel == 0) ? wq : (sel == 1) ? wk : (sel == 2) ? wv : wo;
    dst = wh + (size_t)sel * 262144;
  }
  float4 v = ((const float4*)src)[off];
  ((f16x4*)dst)[off] = pack4(v.x, v.y, v.z, v.w);
}

// ---------------- shared 128x128 B^T GEMM tile core (f16, double-buffered DMA) ----------------
__device__ __forceinline__ void gemm_tile_bt(const _Float16* __restrict__ A,
                                             const _Float16* __restrict__ B,
                                             int m0, int n0,
                                             _Float16* lds,
                                             f32x4 (&acc)[4][4]) {
  const int tid = threadIdx.x;
  const int w = tid >> 6, lane = tid & 63;
  const int wr = w >> 1, wc = w & 1;
  const int lrow = lane & 15, q = lane >> 4;
  const int snb = w * 32 + (lane >> 3);
  const int scb = lane & 7;

#pragma unroll
  for (int i = 0; i < 4; ++i)
#pragma unroll
    for (int j = 0; j < 4; ++j)
#pragma unroll
      for (int r = 0; r < 4; ++r) acc[i][j][r] = 0.f;

#pragma unroll
  for (int t = 0; t < 4; ++t) {
    int n = snb + t * 8;
    int cbg = scb ^ (n & 7);
    GLOAD_LDS16(A + (size_t)(m0 + n) * 512 + cbg * 8, lds + (w * 32 + t * 8) * 64);
    GLOAD_LDS16(B + (size_t)(n0 + n) * 512 + cbg * 8, lds + 8192 + (w * 32 + t * 8) * 64);
  }

  for (int kt = 0; kt < 8; ++kt) {  // K=512, BK=64
    __syncthreads();
    if (kt < 7) {
      _Float16* nb = lds + ((kt + 1) & 1) * 16384;
#pragma unroll
      for (int t = 0; t < 4; ++t) {
        int n = snb + t * 8;
        int cbg = scb ^ (n & 7);
        GLOAD_LDS16(A + (size_t)(m0 + n) * 512 + (kt + 1) * 64 + cbg * 8, nb + (w * 32 + t * 8) * 64);
        GLOAD_LDS16(B + (size_t)(n0 + n) * 512 + (kt + 1) * 64 + cbg * 8, nb + 8192 + (w * 32 + t * 8) * 64);
      }
    }
    _Float16* As = lds + (kt & 1) * 16384;
    _Float16* Bs = As + 8192;

    f16x8 af[4][2], bfr[4][2];
#pragma unroll
    for (int i = 0; i < 4; ++i) {
      int m = wr * 64 + i * 16 + lrow;
#pragma unroll
      for (int kk = 0; kk < 2; ++kk) {
        int cb = (kk * 4 + q) ^ (m & 7);
        af[i][kk] = *(const f16x8*)(As + m * 64 + cb * 8);
      }
    }
#pragma unroll
    for (int j = 0; j < 4; ++j) {
      int n = wc * 64 + j * 16 + lrow;
#pragma unroll
      for (int kk = 0; kk < 2; ++kk) {
        int cb = (kk * 4 + q) ^ (n & 7);
        bfr[j][kk] = *(const f16x8*)(Bs + n * 64 + cb * 8);
      }
    }
#pragma unroll
    for (int i = 0; i < 4; ++i)
#pragma unroll
      for (int j = 0; j < 4; ++j) {
        acc[i][j] = __builtin_amdgcn_mfma_f32_16x16x32_f16(af[i][0], bfr[j][0], acc[i][j], 0, 0, 0);
        acc[i][j] = __builtin_amdgcn_mfma_f32_16x16x32_f16(af[i][1], bfr[j][1], acc[i][j], 0, 0, 0);
      }
  }
}

// ---------------- QKV projection ----------------
__global__ __launch_bounds__(256, 2) void qkv_kernel(
    const _Float16* __restrict__ xb, const _Float16* __restrict__ Wq,
    const _Float16* __restrict__ Wk, const _Float16* __restrict__ Wv,
    _Float16* __restrict__ Qo, _Float16* __restrict__ Ko, _Float16* __restrict__ Vto) {
  __shared__ _Float16 pool[32768];  // 64 KB dbuf staging; bounce [128][136] aliases
  const int z = blockIdx.z;
  f32x4 acc[4][4];
  const int tid = threadIdx.x, w = tid >> 6, lane = tid & 63;
  const int wr = w >> 1, wc = w & 1, lcol = lane & 15, q = lane >> 4;

  if (z < 2) {
    const int m0 = blockIdx.y * 128;  // out-feature tile
    const int n0 = blockIdx.x * 128;  // s tile
    gemm_tile_bt((z == 0) ? Wq : Wk, xb, m0, n0, pool, acc);
    _Float16* outp = (z == 0) ? Qo : Ko;
    __syncthreads();
#pragma unroll
    for (int i = 0; i < 4; ++i) {
      int cl = wr * 64 + i * 16 + q * 4;
#pragma unroll
      for (int j = 0; j < 4; ++j) {
        int s = wc * 64 + j * 16 + lcol;
        *(f16x4*)(pool + s * 136 + cl) =
            pack4(acc[i][j][0], acc[i][j][1], acc[i][j][2], acc[i][j][3]);
      }
    }
    __syncthreads();
#pragma unroll
    for (int it = 0; it < 16; ++it) {
      int srow = it * 8 + (tid >> 5);
      int ch = tid & 31;
      f16x4 v = *(const f16x4*)(pool + srow * 136 + ch * 4);
      *(f16x4*)(outp + (size_t)(n0 + srow) * 512 + m0 + ch * 4) = v;
    }
  } else {
    const int m0 = blockIdx.x * 128;  // s tile
    const int n0 = blockIdx.y * 128;  // feature tile
    gemm_tile_bt(xb, Wv, m0, n0, pool, acc);
    const int bb = m0 >> 11, sl0 = m0 & 2047;
    __syncthreads();
#pragma unroll
    for (int i = 0; i < 4; ++i) {
      int s0 = wr * 64 + i * 16 + q * 4;
#pragma unroll
      for (int j = 0; j < 4; ++j) {
        int c = wc * 64 + j * 16 + lcol;
        *(f16x4*)(pool + c * 136 + s0) =
            pack4(acc[i][j][0], acc[i][j][1], acc[i][j][2], acc[i][j][3]);
      }
    }
    __syncthreads();
#pragma unroll
    for (int it = 0; it < 16; ++it) {
      int crow = it * 8 + (tid >> 5);
      int ch = tid & 31;
      int cg = n0 + crow, h = cg >> 6, d = cg & 63;
      f16x4 v = *(const f16x4*)(pool + crow * 136 + ch * 4);
      *(f16x4*)(Vto + ((size_t)((bb * NHEADS + h) * 64 + d)) * SEQ + sl0 + ch * 4) = v;
    }
  }
}

// ---------------- attention window compute (regs in -> oacc) ----------------
// vb order: [0]=kk0,t0  [1]=kk0,t1  [2]=kk1,t0  [3]=kk1,t1
__device__ __forceinline__ void attn_window(const f16x8 (&ka)[4], const f16x8 (&vb)[4],
                                            const f16x8 (&qb)[4], const f32x16& z16,
                                            f32x16& o0, f32x16& o1) {
  const float c1 = 0.18033688011112042f;  // (1/8)*log2(e); exp2 bias -1 = -11+10 (P x1024)
  __builtin_amdgcn_s_setprio(1);
  f32x16 s = __builtin_amdgcn_mfma_f32_32x32x16_f16(ka[0], qb[0], z16, 0, 0, 0);
  s = __builtin_amdgcn_mfma_f32_32x32x16_f16(ka[1], qb[1], s, 0, 0, 0);
  s = __builtin_amdgcn_mfma_f32_32x32x16_f16(ka[2], qb[2], s, 0, 0, 0);
  s = __builtin_amdgcn_mfma_f32_32x32x16_f16(ka[3], qb[3], s, 0, 0, 0);
  __builtin_amdgcn_s_setprio(0);

  float p[16];
#pragma unroll
  for (int r = 0; r < 16; ++r) {
    float wp = __builtin_amdgcn_exp2f(__builtin_fmaf(s[r], c1, -1.0f));
    float e = wp * 0.0009765625f;
    p[r] = __builtin_fmaf(wp, __builtin_fmaf(e, e, -e), wp);  // wp*(1-e+e^2)
  }

  f16x8 pa0, pa1;
  {
    h16x2 a0 = __builtin_amdgcn_cvt_pkrtz(p[0], p[1]);
    h16x2 a1 = __builtin_amdgcn_cvt_pkrtz(p[2], p[3]);
    h16x2 a2 = __builtin_amdgcn_cvt_pkrtz(p[4], p[5]);
    h16x2 a3 = __builtin_amdgcn_cvt_pkrtz(p[6], p[7]);
    pa0[0] = (_Float16)a0.x; pa0[1] = (_Float16)a0.y;
    pa0[2] = (_Float16)a1.x; pa0[3] = (_Float16)a1.y;
    pa0[4] = (_Float16)a2.x; pa0[5] = (_Float16)a2.y;
    pa0[6] = (_Float16)a3.x; pa0[7] = (_Float16)a3.y;
    h16x2 b0 = __builtin_amdgcn_cvt_pkrtz(p[8], p[9]);
    h16x2 b1 = __builtin_amdgcn_cvt_pkrtz(p[10], p[11]);
    h16x2 b2 = __builtin_amdgcn_cvt_pkrtz(p[12], p[13]);
    h16x2 b3 = __builtin_amdgcn_cvt_pkrtz(p[14], p[15]);
    pa1[0] = (_Float16)b0.x; pa1[1] = (_Float16)b0.y;
    pa1[2] = (_Float16)b1.x; pa1[3] = (_Float16)b1.y;
    pa1[4] = (_Float16)b2.x; pa1[5] = (_Float16)b2.y;
    pa1[6] = (_Float16)b3.x; pa1[7] = (_Float16)b3.y;
  }

  __builtin_amdgcn_s_setprio(1);
  o0 = __builtin_amdgcn_mfma_f32_32x32x16_f16(pa0, vb[0], o0, 0, 0, 0);
  o1 = __builtin_amdgcn_mfma_f32_32x32x16_f16(pa0, vb[1], o1, 0, 0, 0);
  o0 = __builtin_amdgcn_mfma_f32_32x32x16_f16(pa1, vb[2], o0, 0, 0, 0);
  o1 = __builtin_amdgcn_mfma_f32_32x32x16_f16(pa1, vb[3], o1, 0, 0, 0);
  __builtin_amdgcn_s_setprio(0);
}

// ---------------- sigmoid attention: per-wave private k-slice, zero k-loop barriers ----------------
// Grid 1024 = (8 xcd) x (4 bh) x (32 qt). Block: 64 q-rows x 2048 k, 4 waves; wave w
// owns k in [w*512,(w+1)*512) as 16 stages of 32. Each wave DMAs K[32][64]+V[64][32]
// into its PRIVATE LDS double-buffer (coalesced global_load_lds, fixing r7's scatter)
// and gates compute with its own counted vmcnt -- NO __syncthreads in the k-loop
// (fixing r1-r4's all-wave DMA rendezvous). Partial O's (sigmoid attn: k-slices just
// add) are reduced through f32 LDS at the end. All LDS reads conflict-free:
// K/Q chunk ^= (row&7)^(((row>>3)&1)<<2); V (4-chunk rows) chunk ^= (row>>1)&3.
__global__ __launch_bounds__(256, 2) void attn_kernel(
    const _Float16* __restrict__ Qw, const _Float16* __restrict__ Kw,
    const _Float16* __restrict__ Vtw, _Float16* __restrict__ Ow) {
  __shared__ _Float16 lds[36864];  // 72 KB: wave w staging @ w*8192 (dbuf: K 2048h + V 2048h per buf); Q[64][64] @ 32768

  const int tid = threadIdx.x, w = tid >> 6, lane = tid & 63;
  const int q31 = lane & 31, hi = lane >> 5;
  const int l3 = lane >> 3, l7 = lane & 7;
  const int l2 = lane >> 2, l4m = lane & 3;

  // XCD swizzle: 4 bh x 32 q-tiles per XCD (K/V stay L2-resident per XCD)
  const int L = blockIdx.x;
  const int xcd = L & 7, slot = L >> 3;
  const int bh = xcd * 4 + (slot >> 5), qt = slot & 31;
  const int b = bh >> 3, h = bh & 7;
  const int q0 = qt * 64;

  // K A-frag lane->row permutation: swap bits 2,3 of (lane&31); S^T C-regs then feed
  // PV A-frags in order (verified r1-r4).
  const int klp = (q31 & 3) | ((q31 & 4) << 1) | ((q31 & 8) >> 1) | (q31 & 16);
  const int fk = (klp & 7) ^ (((klp >> 3) & 1) << 2);
  const int f2v = (q31 >> 1) & 3;  // V chunk swizzle (same for both d-tiles)

  // per-lane DMA source offsets (stage-invariant)
  int koff[4], voff[4];
#pragma unroll
  for (int t = 0; t < 4; ++t) {
    int kr = t * 8 + l3;
    koff[t] = kr * 1024 + ((l7 ^ ((kr & 7) ^ (((kr >> 3) & 1) << 2))) * 16);
    int vr = t * 16 + l2;
    voff[t] = vr * 4096 + ((l4m ^ ((vr >> 1) & 3)) * 16);
  }
  const char* kgb = (const char*)Kw + ((size_t)(b * SEQ)) * 1024 + h * 128 + (size_t)w * 524288;
  const char* vgb = (const char*)Vtw + (size_t)bh * 262144 + (size_t)w * 1024;
  const char* qgb = (const char*)Qw + ((size_t)(b * SEQ + q0)) * 1024 + h * 128;

  // prologue: cooperative Q stage (2 gloads/wave) + private stage 0; one barrier.
#pragma unroll
  for (int g2 = 0; g2 < 2; ++g2) {
    int g = w * 2 + g2;
    int qr = g * 8 + l3;
    GLOAD_LDS16(qgb + qr * 1024 + ((l7 ^ ((qr & 7) ^ (((qr >> 3) & 1) << 2))) * 16),
                lds + 32768 + g * 512);
  }
  {
    _Float16* nb = lds + w * 8192;  // buf 0
#pragma unroll
    for (int t = 0; t < 4; ++t) GLOAD_LDS16(kgb + koff[t], nb + t * 512);
#pragma unroll
    for (int t = 0; t < 4; ++t) GLOAD_LDS16(vgb + voff[t], nb + 2048 + t * 512);
  }
  __syncthreads();  // drains every wave's own DMA -> Q (and stage 0) landed

  // Q B-frags: 2 q-chunks of 32 rows, 4 d-slices each
  f16x8 qb[2][4];
#pragma unroll
  for (int c = 0; c < 2; ++c) {
    int qr = c * 32 + q31;
    int fq = (qr & 7) ^ (((qr >> 3) & 1) << 2);
#pragma unroll
    for (int s4 = 0; s4 < 4; ++s4) {
      int cb = (s4 * 2 + hi) ^ fq;
      qb[c][s4] = *(const f16x8*)(lds + 32768 + qr * 64 + cb * 8);
    }
  }
  // Q region never rewritten; staging is wave-private -> no second barrier needed.

  f32x16 oacc[2][2], z16;
#pragma unroll
  for (int r = 0; r < 16; ++r) {
    z16[r] = 0.f;
    oacc[0][0][r] = 0.f; oacc[0][1][r] = 0.f;
    oacc[1][0][r] = 0.f; oacc[1][1][r] = 0.f;
  }

  for (int s = 0; s < 16; ++s) {
    if (s < 15) {
      _Float16* nb = lds + w * 8192 + ((s + 1) & 1) * 4096;
      kgb += 32768;  // +32 k-rows
      vgb += 64;     // +32 k-cols (2B each)
#pragma unroll
      for (int t = 0; t < 4; ++t) GLOAD_LDS16(kgb + koff[t], nb + t * 512);
#pragma unroll
      for (int t = 0; t < 4; ++t) GLOAD_LDS16(vgb + voff[t], nb + 2048 + t * 512);
      VMW(8);  // this stage's 8 landed; next stage's 8 in flight
    } else {
      VMW(0);  // last stage: drain (also leaves no DMA outstanding for epilogue)
    }
    const _Float16* kb = lds + w * 8192 + (s & 1) * 4096;
    const _Float16* vbp = kb + 2048;

    f16x8 ka[4], vb[4];
#pragma unroll
    for (int s4 = 0; s4 < 4; ++s4)
      ka[s4] = *(const f16x8*)(kb + klp * 64 + (((s4 * 2 + hi) ^ fk) * 8));
    vb[0] = *(const f16x8*)(vbp + q31 * 32 + (((0 + hi) ^ f2v) * 8));          // kk0 t0
    vb[1] = *(const f16x8*)(vbp + (32 + q31) * 32 + (((0 + hi) ^ f2v) * 8));   // kk0 t1
    vb[2] = *(const f16x8*)(vbp + q31 * 32 + (((2 + hi) ^ f2v) * 8));          // kk1 t0
    vb[3] = *(const f16x8*)(vbp + (32 + q31) * 32 + (((2 + hi) ^ f2v) * 8));   // kk1 t1

    // two independent 32-q chunks: chunk1's QK can interleave with chunk0's sigmoid
    attn_window(ka, vb, qb[0], z16, oacc[0][0], oacc[0][1]);
    attn_window(ka, vb, qb[1], z16, oacc[1][0], oacc[1][1]);
  }

  // epilogue: cross-wave k-slice reduction through f32 LDS, then coalesced f16 stores
  __syncthreads();  // all waves' staging reads done; no DMA outstanding (VMW(0) above)
  float* Of = (float*)lds;  // [4 waves][64 rows][66] f32 = 67.6 KB (overlays staging+Q)
#pragma unroll
  for (int c = 0; c < 2; ++c)
#pragma unroll
    for (int t = 0; t < 2; ++t)
#pragma unroll
      for (int r = 0; r < 16; ++r) {
        int row = c * 32 + (r & 3) + ((r >> 2) << 3) + hi * 4;
        Of[w * 4224 + row * 66 + t * 32 + q31] = oacc[c][t][r] * 0.0009765625f;
      }
  __syncthreads();
#pragma unroll
  for (int i = 0; i < 4; ++i) {
    int o = tid * 16 + i * 4;
    int row = o >> 6, d0 = o & 63;
    float s0 = Of[row * 66 + d0]     + Of[4224 + row * 66 + d0] +
               Of[8448 + row * 66 + d0] + Of[12672 + row * 66 + d0];
    float s1 = Of[row * 66 + d0 + 1] + Of[4224 + row * 66 + d0 + 1] +
               Of[8448 + row * 66 + d0 + 1] + Of[12672 + row * 66 + d0 + 1];
    float s2 = Of[row * 66 + d0 + 2] + Of[4224 + row * 66 + d0 + 2] +
               Of[8448 + row * 66 + d0 + 2] + Of[12672 + row * 66 + d0 + 2];
    float s3 = Of[row * 66 + d0 + 3] + Of[4224 + row * 66 + d0 + 3] +
               Of[8448 + row * 66 + d0 + 3] + Of[12672 + row * 66 + d0 + 3];
    f16x4 v;
    v[0] = (_Float16)s0; v[1] = (_Float16)s1; v[2] = (_Float16)s2; v[3] = (_Float16)s3;
    *(f16x4*)(Ow + (size_t)(b * SEQ + q0 + row) * 512 + h * 64 + d0) = v;
  }
}

// ---------------- output projection (fp32 out, coalesced) ----------------
__global__ __launch_bounds__(256, 2) void oproj_kernel(
    const _Float16* __restrict__ A, const _Float16* __restrict__ Wo,
    float* __restrict__ out) {
  __shared__ _Float16 pool[32768];  // 64 KB dbuf
  const int m0 = blockIdx.x * 128, n0 = blockIdx.y * 128;
  f32x4 acc[4][4];
  gemm_tile_bt(A, Wo, m0, n0, pool, acc);

  const int tid = threadIdx.x, w = tid >> 6, lane = tid & 63;
  const int wr = w >> 1, wc = w & 1, lcol = lane & 15, q = lane >> 4;
#pragma unroll
  for (int i = 0; i < 4; ++i) {
    int gm0 = m0 + wr * 64 + i * 16 + q * 4;
#pragma unroll
    for (int j = 0; j < 4; ++j) {
      int gn = n0 + wc * 64 + j * 16 + lcol;
#pragma unroll
      for (int r = 0; r < 4; ++r)
        out[(size_t)(gm0 + r) * 512 + gn] = acc[i][j][r];
    }
  }
}

// ---------------- launch ----------------
extern "C" void kernel_launch(void* const* d_in, const int* in_sizes, int n_in,
                              void* d_out, int out_size, void* d_ws, size_t ws_size,
                              hipStream_t stream) {
  const float* x = (const float*)d_in[0];
  const float* Wq = (const float*)d_in[1];
  const float* Wk = (const float*)d_in[2];
  const float* Wv = (const float*)d_in[3];
  const float* Wo = (const float*)d_in[4];
  float* out = (float*)d_out;
  char* ws = (char*)d_ws;

  _Float16* xh = (_Float16*)(ws + 0);          // 8 MB [8192][512]
  _Float16* wh = (_Float16*)(ws + 8388608);    // 4 x 512 KB (q,k,v,o)
  _Float16* Qw = (_Float16*)(ws + 10485760);   // 8 MB [8192][512]
  _Float16* Kw = (_Float16*)(ws + 18874368);   // 8 MB [8192][512]
  _Float16* Vtw = (_Float16*)(ws + 27262976);  // 8 MB [B,H,D,S]
  _Float16* Ow = (_Float16*)(ws + 35651584);   // 8 MB [8192][512]

  _Float16* wqh = wh;
  _Float16* wkh = wh + 262144;
  _Float16* wvh = wh + 524288;
  _Float16* woh = wh + 786432;

  cvt_all_kernel<<<5120, 256, 0, stream>>>(x, Wq, Wk, Wv, Wo, xh, wh);
  qkv_kernel<<<dim3(64, 4, 3), 256, 0, stream>>>(xh, wqh, wkh, wvh, Qw, Kw, Vtw);
  attn_kernel<<<1024, 256, 0, stream>>>(Qw, Kw, Vtw, Ow);
  oproj_kernel<<<dim3(64, 4), 256, 0, stream>>>(Ow, woh, out);
}

// Round 10
// 152.562 us; speedup vs baseline: 1.4560x; 1.0220x over previous
//
#include <hip/hip_runtime.h>
#include <stdint.h>

// ---- types ----
typedef _Float16 f16x8 __attribute__((ext_vector_type(8)));
typedef _Float16 f16x4 __attribute__((ext_vector_type(4)));
typedef __fp16 h16x2 __attribute__((ext_vector_type(2)));  // cvt_pkrtz return type
typedef float f32x4 __attribute__((ext_vector_type(4)));
typedef float f32x16 __attribute__((ext_vector_type(16)));

#define SEQ 2048
#define NHEADS 8

// async global->LDS, 16B per lane, LDS dest = wave-uniform base + lane*16
#define GLOAD_LDS16(gp, lp)                                                        \
  __builtin_amdgcn_global_load_lds(                                                \
      (const __attribute__((address_space(1))) void*)(uintptr_t)(const void*)(gp), \
      (__attribute__((address_space(3))) void*)(uintptr_t)(void*)(lp), 16, 0, 0)

// pinned global->reg 16B load (per-lane address), literal offset. "=&v" early-clobber:
// dest must not overlap the dying address operand.
#define GLD16(dst, ptr, imm) \
  asm volatile("global_load_dwordx4 %0, %1, off offset:%c2" : "=&v"(dst) : "v"(ptr), "i"(imm))

// counted vmem wait + scheduler fence (rule #18)
#define VMW(n)                                                     \
  do {                                                             \
    asm volatile("s_waitcnt vmcnt(%c0)" ::"i"(n) : "memory");      \
    __builtin_amdgcn_sched_barrier(0);                             \
  } while (0)

__device__ __forceinline__ f16x4 pack4(float a, float b, float c, float d) {
  h16x2 lo = __builtin_amdgcn_cvt_pkrtz(a, b);
  h16x2 hi = __builtin_amdgcn_cvt_pkrtz(c, d);
  f16x4 o;
  o.x = (_Float16)lo.x; o.y = (_Float16)lo.y;
  o.z = (_Float16)hi.x; o.w = (_Float16)hi.y;
  return o;
}

// ---------------- fp32 -> f16 convert (x + 4 weights, one launch) ----------------
__global__ void cvt_all_kernel(const float* __restrict__ x, const float* __restrict__ wq,
                               const float* __restrict__ wk, const float* __restrict__ wv,
                               const float* __restrict__ wo, _Float16* __restrict__ xh,
                               _Float16* __restrict__ wh) {
  int i = blockIdx.x * 256 + threadIdx.x;  // 0 .. 1310719 (f4 units)
  const float* src;
  _Float16* dst;
  int off;
  if (i < 1048576) {
    src = x; dst = xh; off = i;
  } else {
    int j = i - 1048576;
    int sel = j >> 16;
    off = j & 65535;
    src = (sel == 0) ? wq : (sel == 1) ? wk : (sel == 2) ? wv : wo;
    dst = wh + (size_t)sel * 262144;
  }
  float4 v = ((const float4*)src)[off];
  ((f16x4*)dst)[off] = pack4(v.x, v.y, v.z, v.w);
}

// ---------------- shared 128x128 B^T GEMM tile core (f16, double-buffered DMA) ----------------
__device__ __forceinline__ void gemm_tile_bt(const _Float16* __restrict__ A,
                                             const _Float16* __restrict__ B,
                                             int m0, int n0,
                                             _Float16* lds,
                                             f32x4 (&acc)[4][4]) {
  const int tid = threadIdx.x;
  const int w = tid >> 6, lane = tid & 63;
  const int wr = w >> 1, wc = w & 1;
  const int lrow = lane & 15, q = lane >> 4;
  const int snb = w * 32 + (lane >> 3);
  const int scb = lane & 7;

#pragma unroll
  for (int i = 0; i < 4; ++i)
#pragma unroll
    for (int j = 0; j < 4; ++j)
#pragma unroll
      for (int r = 0; r < 4; ++r) acc[i][j][r] = 0.f;

#pragma unroll
  for (int t = 0; t < 4; ++t) {
    int n = snb + t * 8;
    int cbg = scb ^ (n & 7);
    GLOAD_LDS16(A + (size_t)(m0 + n) * 512 + cbg * 8, lds + (w * 32 + t * 8) * 64);
    GLOAD_LDS16(B + (size_t)(n0 + n) * 512 + cbg * 8, lds + 8192 + (w * 32 + t * 8) * 64);
  }

  for (int kt = 0; kt < 8; ++kt) {  // K=512, BK=64
    __syncthreads();
    if (kt < 7) {
      _Float16* nb = lds + ((kt + 1) & 1) * 16384;
#pragma unroll
      for (int t = 0; t < 4; ++t) {
        int n = snb + t * 8;
        int cbg = scb ^ (n & 7);
        GLOAD_LDS16(A + (size_t)(m0 + n) * 512 + (kt + 1) * 64 + cbg * 8, nb + (w * 32 + t * 8) * 64);
        GLOAD_LDS16(B + (size_t)(n0 + n) * 512 + (kt + 1) * 64 + cbg * 8, nb + 8192 + (w * 32 + t * 8) * 64);
      }
    }
    _Float16* As = lds + (kt & 1) * 16384;
    _Float16* Bs = As + 8192;

    f16x8 af[4][2], bfr[4][2];
#pragma unroll
    for (int i = 0; i < 4; ++i) {
      int m = wr * 64 + i * 16 + lrow;
#pragma unroll
      for (int kk = 0; kk < 2; ++kk) {
        int cb = (kk * 4 + q) ^ (m & 7);
        af[i][kk] = *(const f16x8*)(As + m * 64 + cb * 8);
      }
    }
#pragma unroll
    for (int j = 0; j < 4; ++j) {
      int n = wc * 64 + j * 16 + lrow;
#pragma unroll
      for (int kk = 0; kk < 2; ++kk) {
        int cb = (kk * 4 + q) ^ (n & 7);
        bfr[j][kk] = *(const f16x8*)(Bs + n * 64 + cb * 8);
      }
    }
#pragma unroll
    for (int i = 0; i < 4; ++i)
#pragma unroll
      for (int j = 0; j < 4; ++j) {
        acc[i][j] = __builtin_amdgcn_mfma_f32_16x16x32_f16(af[i][0], bfr[j][0], acc[i][j], 0, 0, 0);
        acc[i][j] = __builtin_amdgcn_mfma_f32_16x16x32_f16(af[i][1], bfr[j][1], acc[i][j], 0, 0, 0);
      }
  }
}

// ---------------- QKV projection -> FRAGMENT-LINEAR outputs (coalesced record stores) ----------------
// Q/K/V stored in the exact per-wave-load order attn consumes: 2048-half records
// (one per (head, 32-row block)). K bakes in the bit2<->3 lane-row permutation.
//   QF/KF record (b,h,blk): elem s4*512 + ((hi<<5)|l32)*8 + j =
//     T[b][blk*32 + perm(l32)][h][d = s4*16 + hi*8 + j]   (perm: id for Q, bit2<->3 for K)
//   VF record (b,h,mi):  elem (kk*2+t)*512 + ((hi<<5)|qq)*8 + j =
//     V^T[b][h][d = t*32 + qq][k = mi*32 + kk*16 + hi*8 + j]
// Each 128x128 output tile = exactly 8 complete records -> scatter via LDS, then
// 8 fully-coalesced 4 KB record copies.
__global__ __launch_bounds__(256, 2) void qkv_kernel(
    const _Float16* __restrict__ xb, const _Float16* __restrict__ Wq,
    const _Float16* __restrict__ Wk, const _Float16* __restrict__ Wv,
    _Float16* __restrict__ Qo, _Float16* __restrict__ Ko, _Float16* __restrict__ Vto) {
  __shared__ _Float16 pool[32768];  // 64 KB dbuf staging; records overlay (16 K halves)
  const int z = blockIdx.z;
  f32x4 acc[4][4];
  const int tid = threadIdx.x, w = tid >> 6, lane = tid & 63;
  const int wr = w >> 1, wc = w & 1, lcol = lane & 15, q = lane >> 4;

  if (z < 2) {
    const int m0 = blockIdx.y * 128;  // out-feature tile (2 heads)
    const int n0 = blockIdx.x * 128;  // s tile (4 blk32)
    gemm_tile_bt((z == 0) ? Wq : Wk, xb, m0, n0, pool, acc);
    _Float16* outp = (z == 0) ? Qo : Ko;
    __syncthreads();  // gemm reads done; pool becomes 8 records x 2048 halves
#pragma unroll
    for (int i = 0; i < 4; ++i) {
      int cl = wr * 64 + i * 16 + q * 4;  // feature-local
      int hh_l = cl >> 6, dd = cl & 63;
      int s4 = dd >> 4, hi2 = (dd >> 3) & 1, j0 = dd & 7;
#pragma unroll
      for (int j = 0; j < 4; ++j) {
        int s = wc * 64 + j * 16 + lcol;  // s-local
        int blk = s >> 5, r32 = s & 31;
        int l32 = (z == 0) ? r32
                           : ((r32 & 3) | ((r32 & 4) << 1) | ((r32 & 8) >> 1) | (r32 & 16));
        *(f16x4*)(pool + (hh_l * 4 + blk) * 2048 + s4 * 512 + ((hi2 << 5) | l32) * 8 + j0) =
            pack4(acc[i][j][0], acc[i][j][1], acc[i][j][2], acc[i][j][3]);
      }
    }
    __syncthreads();
    {
      int b2 = n0 >> 11, sblk0 = (n0 & 2047) >> 5, hh0 = m0 >> 6;
#pragma unroll
      for (int rec = 0; rec < 8; ++rec) {
        int hh_l = rec >> 2, blk = rec & 3;
        size_t goff = (size_t)(b2 * NHEADS + hh0 + hh_l) * 131072 +
                      (size_t)(sblk0 + blk) * 2048;
        f16x8 vv = *(const f16x8*)(pool + rec * 2048 + tid * 8);
        *(f16x8*)(outp + goff + tid * 8) = vv;
      }
    }
  } else {
    const int m0 = blockIdx.x * 128;  // s (=k) tile (4 mi records)
    const int n0 = blockIdx.y * 128;  // feature tile (2 heads)
    gemm_tile_bt(xb, Wv, m0, n0, pool, acc);
    const int bb = m0 >> 11;
    __syncthreads();
#pragma unroll
    for (int i = 0; i < 4; ++i) {
      int s0 = wr * 64 + i * 16 + q * 4;  // k-local
      int mi_l = s0 >> 5, kk = (s0 >> 4) & 1, hi2 = (s0 >> 3) & 1, j0 = s0 & 7;
#pragma unroll
      for (int j = 0; j < 4; ++j) {
        int c = wc * 64 + j * 16 + lcol;  // d-feature-local
        int hh_l = c >> 6, dd = c & 63;
        int t = dd >> 5, qq = dd & 31;
        *(f16x4*)(pool + (hh_l * 4 + mi_l) * 2048 + (kk * 2 + t) * 512 + ((hi2 << 5) | qq) * 8 + j0) =
            pack4(acc[i][j][0], acc[i][j][1], acc[i][j][2], acc[i][j][3]);
      }
    }
    __syncthreads();
    {
      int kblk0 = (m0 & 2047) >> 5, hh0 = n0 >> 6;
#pragma unroll
      for (int rec = 0; rec < 8; ++rec) {
        int hh_l = rec >> 2, mi_l = rec & 3;
        size_t goff = (size_t)(bb * NHEADS + hh0 + hh_l) * 131072 +
                      (size_t)(kblk0 + mi_l) * 2048;
        f16x8 vv = *(const f16x8*)(pool + rec * 2048 + tid * 8);
        *(f16x8*)(Vto + goff + tid * 8) = vv;
      }
    }
  }
}

// ---------------- attention window compute (regs in -> oacc) ----------------
// vb order: [0]=kk0,t0  [1]=kk0,t1  [2]=kk1,t0  [3]=kk1,t1
__device__ __forceinline__ void attn_window(const f16x8 (&ka)[4], const f16x8 (&vb)[4],
                                            const f16x8 (&qb)[4], const f32x16& z16,
                                            f32x16& o0, f32x16& o1) {
  const float c1 = 0.18033688011112042f;  // (1/8)*log2(e); exp2 bias -1 = -11+10 (P x1024)
  __builtin_amdgcn_s_setprio(1);
  f32x16 s = __builtin_amdgcn_mfma_f32_32x32x16_f16(ka[0], qb[0], z16, 0, 0, 0);
  s = __builtin_amdgcn_mfma_f32_32x32x16_f16(ka[1], qb[1], s, 0, 0, 0);
  s = __builtin_amdgcn_mfma_f32_32x32x16_f16(ka[2], qb[2], s, 0, 0, 0);
  s = __builtin_amdgcn_mfma_f32_32x32x16_f16(ka[3], qb[3], s, 0, 0, 0);
  __builtin_amdgcn_s_setprio(0);

  float p[16];
#pragma unroll
  for (int r = 0; r < 16; ++r) {
    float wp = __builtin_amdgcn_exp2f(__builtin_fmaf(s[r], c1, -1.0f));
    float e = wp * 0.0009765625f;
    p[r] = __builtin_fmaf(wp, __builtin_fmaf(e, e, -e), wp);  // wp*(1-e+e^2)
  }

  f16x8 pa0, pa1;
  {
    h16x2 a0 = __builtin_amdgcn_cvt_pkrtz(p[0], p[1]);
    h16x2 a1 = __builtin_amdgcn_cvt_pkrtz(p[2], p[3]);
    h16x2 a2 = __builtin_amdgcn_cvt_pkrtz(p[4], p[5]);
    h16x2 a3 = __builtin_amdgcn_cvt_pkrtz(p[6], p[7]);
    pa0[0] = (_Float16)a0.x; pa0[1] = (_Float16)a0.y;
    pa0[2] = (_Float16)a1.x; pa0[3] = (_Float16)a1.y;
    pa0[4] = (_Float16)a2.x; pa0[5] = (_Float16)a2.y;
    pa0[6] = (_Float16)a3.x; pa0[7] = (_Float16)a3.y;
    h16x2 b0 = __builtin_amdgcn_cvt_pkrtz(p[8], p[9]);
    h16x2 b1 = __builtin_amdgcn_cvt_pkrtz(p[10], p[11]);
    h16x2 b2 = __builtin_amdgcn_cvt_pkrtz(p[12], p[13]);
    h16x2 b3 = __builtin_amdgcn_cvt_pkrtz(p[14], p[15]);
    pa1[0] = (_Float16)b0.x; pa1[1] = (_Float16)b0.y;
    pa1[2] = (_Float16)b1.x; pa1[3] = (_Float16)b1.y;
    pa1[4] = (_Float16)b2.x; pa1[5] = (_Float16)b2.y;
    pa1[6] = (_Float16)b3.x; pa1[7] = (_Float16)b3.y;
  }

  __builtin_amdgcn_s_setprio(1);
  o0 = __builtin_amdgcn_mfma_f32_32x32x16_f16(pa0, vb[0], o0, 0, 0, 0);
  o1 = __builtin_amdgcn_mfma_f32_32x32x16_f16(pa0, vb[1], o1, 0, 0, 0);
  o0 = __builtin_amdgcn_mfma_f32_32x32x16_f16(pa1, vb[2], o0, 0, 0, 0);
  o1 = __builtin_amdgcn_mfma_f32_32x32x16_f16(pa1, vb[3], o1, 0, 0, 0);
  __builtin_amdgcn_s_setprio(0);
}

// issue one window's 8 fragment loads (fragment-linear: each is 64x16B CONTIGUOUS),
// then bump pointers by 2 windows (depth-2 A/B rotation).
#define ISSUE_WIN(KA, VB, KP, VP)  \
  do {                             \
    GLD16(KA[0], KP, 0);           \
    GLD16(KA[1], KP, 1024);        \
    GLD16(KA[2], KP, 2048);        \
    GLD16(KA[3], KP, 3072);        \
    GLD16(VB[0], VP, 0);           \
    GLD16(VB[1], VP, 1024);        \
    GLD16(VB[2], VP, 2048);        \
    GLD16(VB[3], VP, 3072);        \
    KP += 8192;                    \
    VP += 8192;                    \
  } while (0)

// ---------------- sigmoid attention: coalesced barrier-free streaming, 3 waves/SIMD ----------------
// Grid 1024 = (8 xcd) x (4 bh) x (32 qt of 64 q). Block: 256 thr, 4 waves =
// (2 q-chunks of 32) x (2 k-halves of 1024). Q/K/V are FRAGMENT-LINEAR in global
// (written by qkv), so every load is one contiguous 1 KB wave-load: no LDS staging,
// no ds_reads, no bank conflicts, no k-loop barriers. launch_bounds(256,3): 168-VGPR
// budget fits the pinned-asm working set (r9's (256,4)=128 cap is the suspected
// register-allocation failure); 3 blocks/CU -> 3 fully independent waves/SIMD.
// k-half partials reduce through f32 LDS at the end (sigmoid attn: partials add).
__global__ __launch_bounds__(256, 3) void attn_kernel(
    const _Float16* __restrict__ QF, const _Float16* __restrict__ KF,
    const _Float16* __restrict__ VF, _Float16* __restrict__ Ow) {
  __shared__ float Of[8704];  // [2 kh][64 rows][68] f32 = 34 KB (epilogue only)

  const int tid = threadIdx.x, wv = tid >> 6, lane = tid & 63;
  const int q31 = lane & 31, hi = lane >> 5;

  // XCD swizzle: 4 bh x 32 q-tiles per XCD
  const int L = blockIdx.x;
  const int xcd = L & 7, slot = L >> 3;
  const int bh = xcd * 4 + (slot >> 5), qt = slot & 31;
  const int b = bh >> 3, h = bh & 7;
  const int q0 = qt * 64;

  const int qi = wv & 1;   // q-chunk of 32 rows
  const int kh = wv >> 1;  // k-half: windows [kh*32, kh*32+32)
  const int qc = qt * 2 + qi;

  const char* qp = (const char*)QF + (size_t)bh * 262144 + qc * 4096 + lane * 16;
  const char* kpA = (const char*)KF + (size_t)bh * 262144 + (size_t)kh * 131072 + lane * 16;
  const char* kpB = kpA + 4096;
  const char* vpA = (const char*)VF + (size_t)bh * 262144 + (size_t)kh * 131072 + lane * 16;
  const char* vpB = vpA + 4096;

  f16x8 qb[4];
  GLD16(qb[0], qp, 0);
  GLD16(qb[1], qp, 1024);
  GLD16(qb[2], qp, 2048);
  GLD16(qb[3], qp, 3072);

  f16x8 kaA[4], vbA[4], kaB[4], vbB[4];
  ISSUE_WIN(kaA, vbA, kpA, vpA);  // W0
  ISSUE_WIN(kaB, vbB, kpB, vpB);  // W1

  f32x16 oacc0, oacc1, z16;
#pragma unroll
  for (int r = 0; r < 16; ++r) { z16[r] = 0.f; oacc0[r] = 0.f; oacc1[r] = 0.f; }

  // 32 windows = 16 A/B pairs; steady state holds 16 outstanding, waits to 8.
  for (int i = 0; i < 15; ++i) {
    VMW(8);  // A landed (first iter: Q + A)
    attn_window(kaA, vbA, qb, z16, oacc0, oacc1);
    ISSUE_WIN(kaA, vbA, kpA, vpA);
    VMW(8);  // B landed
    attn_window(kaB, vbB, qb, z16, oacc0, oacc1);
    ISSUE_WIN(kaB, vbB, kpB, vpB);
  }
  VMW(8);
  attn_window(kaA, vbA, qb, z16, oacc0, oacc1);
  VMW(0);
  attn_window(kaB, vbB, qb, z16, oacc0, oacc1);

  // epilogue: f32 partials to LDS, cross-kh reduce, coalesced f16 stores
#pragma unroll
  for (int t = 0; t < 2; ++t) {
#pragma unroll
    for (int r = 0; r < 16; ++r) {
      int row = qi * 32 + (r & 3) + ((r >> 2) << 3) + hi * 4;
      int d = t * 32 + q31;
      float v = (t == 0) ? oacc0[r] : oacc1[r];
      Of[kh * 4352 + row * 68 + d] = v * 0.0009765625f;
    }
  }
  __syncthreads();
#pragma unroll
  for (int i = 0; i < 4; ++i) {
    int o = tid * 16 + i * 4;
    int row = o >> 6, d0 = o & 63;
    f32x4 a = *(const f32x4*)(Of + row * 68 + d0);
    f32x4 c = *(const f32x4*)(Of + 4352 + row * 68 + d0);
    f16x4 v;
    v[0] = (_Float16)(a[0] + c[0]);
    v[1] = (_Float16)(a[1] + c[1]);
    v[2] = (_Float16)(a[2] + c[2]);
    v[3] = (_Float16)(a[3] + c[3]);
    *(f16x4*)(Ow + (size_t)(b * SEQ + q0 + row) * 512 + h * 64 + d0) = v;
  }
}

// ---------------- output projection (fp32 out, coalesced) ----------------
__global__ __launch_bounds__(256, 2) void oproj_kernel(
    const _Float16* __restrict__ A, const _Float16* __restrict__ Wo,
    float* __restrict__ out) {
  __shared__ _Float16 pool[32768];  // 64 KB dbuf
  const int m0 = blockIdx.x * 128, n0 = blockIdx.y * 128;
  f32x4 acc[4][4];
  gemm_tile_bt(A, Wo, m0, n0, pool, acc);

  const int tid = threadIdx.x, w = tid >> 6, lane = tid & 63;
  const int wr = w >> 1, wc = w & 1, lcol = lane & 15, q = lane >> 4;
#pragma unroll
  for (int i = 0; i < 4; ++i) {
    int gm0 = m0 + wr * 64 + i * 16 + q * 4;
#pragma unroll
    for (int j = 0; j < 4; ++j) {
      int gn = n0 + wc * 64 + j * 16 + lcol;
#pragma unroll
      for (int r = 0; r < 4; ++r)
        out[(size_t)(gm0 + r) * 512 + gn] = acc[i][j][r];
    }
  }
}

// ---------------- launch ----------------
extern "C" void kernel_launch(void* const* d_in, const int* in_sizes, int n_in,
                              void* d_out, int out_size, void* d_ws, size_t ws_size,
                              hipStream_t stream) {
  const float* x = (const float*)d_in[0];
  const float* Wq = (const float*)d_in[1];
  const float* Wk = (const float*)d_in[2];
  const float* Wv = (const float*)d_in[3];
  const float* Wo = (const float*)d_in[4];
  float* out = (float*)d_out;
  char* ws = (char*)d_ws;

  _Float16* xh = (_Float16*)(ws + 0);          // 8 MB [8192][512]
  _Float16* wh = (_Float16*)(ws + 8388608);    // 4 x 512 KB (q,k,v,o)
  _Float16* Qw = (_Float16*)(ws + 10485760);   // 8 MB Q fragment-linear
  _Float16* Kw = (_Float16*)(ws + 18874368);   // 8 MB K fragment-linear
  _Float16* Vtw = (_Float16*)(ws + 27262976);  // 8 MB V fragment-linear
  _Float16* Ow = (_Float16*)(ws + 35651584);   // 8 MB [8192][512]

  _Float16* wqh = wh;
  _Float16* wkh = wh + 262144;
  _Float16* wvh = wh + 524288;
  _Float16* woh = wh + 786432;

  cvt_all_kernel<<<5120, 256, 0, stream>>>(x, Wq, Wk, Wv, Wo, xh, wh);
  qkv_kernel<<<dim3(64, 4, 3), 256, 0, stream>>>(xh, wqh, wkh, wvh, Qw, Kw, Vtw);
  attn_kernel<<<1024, 256, 0, stream>>>(Qw, Kw, Vtw, Ow);
  oproj_kernel<<<dim3(64, 4), 256, 0, stream>>>(Ow, woh, out);
}